// Round 3
// baseline (776.178 us; speedup 1.0000x reference)
//
#include <hip/hip_runtime.h>
#include <hip/hip_bf16.h>
#include <math.h>

namespace {

constexpr int NTOK   = 4096;   // B*T
constexpr int DDIM   = 1024;
constexpr int E      = 8;
constexpr int HDIM   = 2048;
constexpr int MAXROWS = 8192;  // NTOK * K (every token -> exactly 2 rows)

typedef __bf16 bf16;
typedef __attribute__((ext_vector_type(4))) __bf16 bf16x4;
typedef __attribute__((ext_vector_type(8))) __bf16 bf16x8;
typedef __attribute__((ext_vector_type(4))) float floatx4;

// async global->LDS, 16B per lane; LDS dest = wave-uniform base + lane*16
__device__ inline void gload_lds16(const bf16* g, bf16* l) {
  __builtin_amdgcn_global_load_lds(
      (const __attribute__((address_space(1))) void*)g,
      (__attribute__((address_space(3))) void*)l, 16, 0, 0);
}

// ---------------- init ----------------
__global__ void init_kernel(int* counts) {
  if (threadIdx.x < E) counts[threadIdx.x] = 0;
}

// ------- router: fp32 logits -> top2 + gates; also writes bf16 cast of x -------
__global__ void router_kernel(const float* __restrict__ x,
                              const float* __restrict__ Wr,
                              const float* __restrict__ br,
                              int* __restrict__ counts,
                              int* __restrict__ topk_e,
                              float* __restrict__ topk_g,
                              bf16* __restrict__ xb) {
  int wave = threadIdx.x >> 6;
  int lane = threadIdx.x & 63;
  int t = blockIdx.x * 4 + wave;   // grid = NTOK/4, exact
  const float* xr = x + (size_t)t * DDIM;
  bf16* xbr = xb + (size_t)t * DDIM;

  float acc[E];
#pragma unroll
  for (int e = 0; e < E; ++e) acc[e] = 0.f;

#pragma unroll
  for (int i = 0; i < DDIM / 256; ++i) {
    int d0 = i * 256 + lane * 4;
    float4 xv = *(const float4*)(xr + d0);
    float xa[4];
    *(float4*)xa = xv;
    bf16x4 xc;
    xc[0] = (bf16)xv.x; xc[1] = (bf16)xv.y; xc[2] = (bf16)xv.z; xc[3] = (bf16)xv.w;
    *(bf16x4*)(xbr + d0) = xc;      // fused fp32->bf16 cast of x
#pragma unroll
    for (int j = 0; j < 4; ++j) {
      float xs = xa[j];
      float4 w0 = *(const float4*)(Wr + (size_t)(d0 + j) * E);
      float4 w1 = *(const float4*)(Wr + (size_t)(d0 + j) * E + 4);
      acc[0] += xs * w0.x; acc[1] += xs * w0.y;
      acc[2] += xs * w0.z; acc[3] += xs * w0.w;
      acc[4] += xs * w1.x; acc[5] += xs * w1.y;
      acc[6] += xs * w1.z; acc[7] += xs * w1.w;
    }
  }
#pragma unroll
  for (int off = 32; off > 0; off >>= 1) {
#pragma unroll
    for (int e = 0; e < E; ++e) acc[e] += __shfl_xor(acc[e], off, 64);
  }
  if (lane == 0) {
    float lg[E];
#pragma unroll
    for (int e = 0; e < E; ++e) lg[e] = acc[e] + br[e];
    int e0 = 0;
#pragma unroll
    for (int e = 1; e < E; ++e) if (lg[e] > lg[e0]) e0 = e;
    int e1 = (e0 == 0) ? 1 : 0;
#pragma unroll
    for (int e = 0; e < E; ++e) if (e != e0 && lg[e] > lg[e1]) e1 = e;
    float ex = expf(lg[e1] - lg[e0]);
    float s = 1.f + ex;
    topk_e[2 * t]     = e0;
    topk_e[2 * t + 1] = e1;
    topk_g[2 * t]     = 1.f / s;
    topk_g[2 * t + 1] = ex / s;
    atomicAdd(&counts[e0], 1);
    atomicAdd(&counts[e1], 1);
  }
}

// ---------------- scan: offsets + cursors ----------------
__global__ void scan_kernel(const int* __restrict__ counts,
                            int* __restrict__ offsets,
                            int* __restrict__ cursor) {
  if (threadIdx.x == 0 && blockIdx.x == 0) {
    int s = 0;
    for (int e = 0; e < E; ++e) { offsets[e] = s; cursor[e] = s; s += counts[e]; }
    offsets[E] = s;
  }
}

// ---------------- scatter: build permuted row space ----------------
__global__ void scatter_kernel(const int* __restrict__ topk_e,
                               int* __restrict__ cursor,
                               int* __restrict__ rowtok,
                               int* __restrict__ tokrow) {
  int t = blockIdx.x * 256 + threadIdx.x;   // grid = NTOK/256, exact
#pragma unroll
  for (int k = 0; k < 2; ++k) {
    int e = topk_e[2 * t + k];
    int row = atomicAdd(&cursor[e], 1);
    rowtok[row] = t;
    tokrow[2 * t + k] = row;
  }
}

// -------- batched transpose+cast: fp32 in [batch][R][C] -> bf16 out [batch][C][R] --------
__global__ void transpose_cast_kernel(const float* __restrict__ in, bf16* __restrict__ out,
                                      int R, int C) {
  __shared__ bf16 tile[64][72];
  const float* src = in + (size_t)blockIdx.z * R * C;
  bf16* dst = out + (size_t)blockIdx.z * R * C;
  int c0 = blockIdx.x * 64, r0 = blockIdx.y * 64;
  int tr = threadIdx.x >> 4;          // 0..15
  int tc = (threadIdx.x & 15) * 4;    // 0..60
#pragma unroll
  for (int i = 0; i < 4; ++i) {
    int r = tr + i * 16;
    float4 v = *(const float4*)(src + (size_t)(r0 + r) * C + c0 + tc);
    bf16x4 o;
    o[0] = (bf16)v.x; o[1] = (bf16)v.y; o[2] = (bf16)v.z; o[3] = (bf16)v.w;
    *(bf16x4*)&tile[r][tc] = o;
  }
  __syncthreads();
  int tr2 = threadIdx.x >> 3;         // 0..31
  int tc2 = (threadIdx.x & 7) * 8;    // 0..56
#pragma unroll
  for (int i = 0; i < 2; ++i) {
    int c = tr2 + i * 32;
    bf16x8 v;
#pragma unroll
    for (int j = 0; j < 8; ++j) v[j] = tile[tc2 + j][c];
    *(bf16x8*)(dst + (size_t)(c0 + c) * R + r0 + tc2) = v;
  }
}

// ---------------- grouped FFN GEMM (m97 structure: 128x128xBK64, async LDS) -------------
// Y[row, n] = act( A_row . W[e][n][:] + bias[e][n] )
// A rows (bf16): GATHER ? X[rowtok[row]] : A[row]   (K-contiguous)
// W (bf16): [E][Ndim][Kdim]  (pre-transposed, K contiguous); bias fp32 [E][Ndim]
template <bool GATHER, bool RELU>
__global__ __launch_bounds__(256) void ffn_gemm(
    const bf16* __restrict__ A, const bf16* __restrict__ W,
    const float* __restrict__ bias, bf16* __restrict__ Y,
    const int* __restrict__ rowtok, const int* __restrict__ offsets,
    const int* __restrict__ counts, int Kdim, int Ndim) {
  int e = blockIdx.z;
  int cnt = counts[e];
  int mBase = blockIdx.x * 128;
  if (mBase >= cnt) return;
  int rowBase = offsets[e] + mBase;
  int nBase = blockIdx.y * 128;
  int validRows = cnt - mBase; if (validRows > 128) validRows = 128;

  // unpadded: layout must match global_load_lds lane order (base + lane*16)
  __shared__ bf16 Asm[128 * 64];
  __shared__ bf16 Bsm[128 * 64];

  int tid = threadIdx.x;
  int wave = tid >> 6, lane = tid & 63;
  int lrow = lane >> 3;     // 0..7  row within 8-row chunk
  int lseg = lane & 7;      // 16B segment within 128B row

  // staging pointers: chunk c = wave + i*4 covers rows [c*8, c*8+8)
  const bf16* aptr[4];
  const bf16* bptr[4];
#pragma unroll
  for (int i = 0; i < 4; ++i) {
    int c = wave + i * 4;
    int r = rowBase + c * 8 + lrow;
    if (r > MAXROWS - 1) r = MAXROWS - 1;   // partial tile: harmless dup, masked at store
    size_t rowoff = GATHER ? (size_t)rowtok[r] * Kdim : (size_t)r * Kdim;
    aptr[i] = A + rowoff + lseg * 8;
    bptr[i] = W + ((size_t)e * Ndim + nBase + c * 8 + lrow) * (size_t)Kdim + lseg * 8;
  }

  floatx4 acc[4][4];
#pragma unroll
  for (int m = 0; m < 4; ++m)
#pragma unroll
    for (int n = 0; n < 4; ++n) acc[m][n] = floatx4{0.f, 0.f, 0.f, 0.f};

  int wm = wave & 1, wn = wave >> 1;        // 2x2 wave grid, each wave 64x64
  int mrow = lane & 15;
  int kgrp = (lane >> 4) * 8;

  for (int kc = 0; kc < Kdim; kc += 64) {
#pragma unroll
    for (int i = 0; i < 4; ++i) {
      int c = wave + i * 4;
      gload_lds16(aptr[i] + kc, Asm + c * 512);
      gload_lds16(bptr[i] + kc, Bsm + c * 512);
    }
    __syncthreads();   // drains vmcnt -> LDS tiles complete & visible
#pragma unroll
    for (int ks = 0; ks < 2; ++ks) {
      int k0 = ks * 32 + kgrp;
      bf16x8 af[4], bf[4];
#pragma unroll
      for (int m = 0; m < 4; ++m)
        af[m] = *(const bf16x8*)&Asm[(wm * 64 + m * 16 + mrow) * 64 + k0];
#pragma unroll
      for (int n = 0; n < 4; ++n)
        bf[n] = *(const bf16x8*)&Bsm[(wn * 64 + n * 16 + mrow) * 64 + k0];
#pragma unroll
      for (int m = 0; m < 4; ++m)
#pragma unroll
        for (int n = 0; n < 4; ++n)
          acc[m][n] = __builtin_amdgcn_mfma_f32_16x16x32_bf16(af[m], bf[n], acc[m][n], 0, 0, 0);
    }
    __syncthreads();   // all frag reads done before next iter's overwrite
  }

  // epilogue: C/D layout col=lane&15, row=(lane>>4)*4+reg  [m89-verified]
  int crow = (lane >> 4) * 4;
  int ccol = lane & 15;
#pragma unroll
  for (int n = 0; n < 4; ++n) {
    int colg = nBase + wn * 64 + n * 16 + ccol;
    float bv = bias[(size_t)e * Ndim + colg];
#pragma unroll
    for (int m = 0; m < 4; ++m) {
#pragma unroll
      for (int r = 0; r < 4; ++r) {
        int rl = wm * 64 + m * 16 + crow + r;
        if (rl < validRows) {
          float v = acc[m][n][r] + bv;
          if (RELU) v = fmaxf(v, 0.f);
          Y[(size_t)(rowBase + rl) * Ndim + colg] = (bf16)v;
        }
      }
    }
  }
}

// ---------------- combine: out[t] = g0*Y2[r0] + g1*Y2[r1]  (fp32 out) ----------------
__global__ void combine_kernel(const bf16* __restrict__ Y2,
                               const int* __restrict__ tokrow,
                               const float* __restrict__ topk_g,
                               float* __restrict__ out) {
  int idx = blockIdx.x * 256 + threadIdx.x;
  int t = idx >> 7;              // DDIM/8 = 128 vectors per token
  int d8 = (idx & 127) * 8;
  int r0 = tokrow[2 * t], r1 = tokrow[2 * t + 1];
  float g0 = topk_g[2 * t], g1 = topk_g[2 * t + 1];
  bf16x8 a = *(const bf16x8*)(Y2 + (size_t)r0 * DDIM + d8);
  bf16x8 b = *(const bf16x8*)(Y2 + (size_t)r1 * DDIM + d8);
  float o[8];
#pragma unroll
  for (int j = 0; j < 8; ++j) o[j] = g0 * (float)a[j] + g1 * (float)b[j];
  float* op = out + (size_t)t * DDIM + d8;
  *(float4*)op = *(float4*)&o[0];
  *(float4*)(op + 4) = *(float4*)&o[4];
}

}  // namespace

extern "C" void kernel_launch(void* const* d_in, const int* in_sizes, int n_in,
                              void* d_out, int out_size, void* d_ws, size_t ws_size,
                              hipStream_t stream) {
  const float* x  = (const float*)d_in[0];   // [B,T,D] fp32
  const float* Wr = (const float*)d_in[1];   // [D,E]   fp32
  const float* br = (const float*)d_in[2];   // [E]     fp32
  const float* W1 = (const float*)d_in[3];   // [E,D,H] fp32
  const float* b1 = (const float*)d_in[4];   // [E,H]   fp32
  const float* W2 = (const float*)d_in[5];   // [E,H,D] fp32
  const float* b2 = (const float*)d_in[6];   // [E,D]   fp32
  float* out = (float*)d_out;                // [B,T,D] fp32

  char* w = (char*)d_ws;
  int*   counts  = (int*)(w);
  int*   offsets = (int*)(w + 256);
  int*   cursor  = (int*)(w + 512);
  int*   topk_e  = (int*)(w + 1024);
  float* topk_g  = (float*)(w + 1024 + 32768);
  int*   rowtok  = (int*)(w + 1024 + 65536);
  int*   tokrow  = (int*)(w + 1024 + 98304);
  char*  big     = w + 1024 + 131072;
  bf16* xb  = (bf16*)(big);                        // [4096][D]  bf16   8.4 MB
  bf16* W1T = (bf16*)(big + 8388608);              // [E][H][D]  bf16  33.5 MB
  bf16* W2T = (bf16*)(big + 8388608 + 33554432);   // [E][D][H]  bf16  33.5 MB
  bf16* Y1  = (bf16*)(big + 8388608 + 67108864);   // [8192][H]  bf16  33.5 MB
  bf16* Y2  = (bf16*)(big + 8388608);              // alias W1T (dead after GEMM1)

  init_kernel<<<1, 64, 0, stream>>>(counts);
  transpose_cast_kernel<<<dim3(HDIM / 64, DDIM / 64, E), 256, 0, stream>>>(W1, W1T, DDIM, HDIM);
  transpose_cast_kernel<<<dim3(DDIM / 64, HDIM / 64, E), 256, 0, stream>>>(W2, W2T, HDIM, DDIM);
  router_kernel<<<NTOK / 4, 256, 0, stream>>>(x, Wr, br, counts, topk_e, topk_g, xb);
  scan_kernel<<<1, 1, 0, stream>>>(counts, offsets, cursor);
  scatter_kernel<<<NTOK / 256, 256, 0, stream>>>(topk_e, cursor, rowtok, tokrow);
  ffn_gemm<true, true><<<dim3(64, HDIM / 128, E), 256, 0, stream>>>(
      xb, W1T, b1, Y1, rowtok, offsets, counts, DDIM, HDIM);
  ffn_gemm<false, false><<<dim3(64, DDIM / 128, E), 256, 0, stream>>>(
      Y1, W2T, b2, Y2, rowtok, offsets, counts, HDIM, DDIM);
  combine_kernel<<<NTOK * DDIM / 8 / 256, 256, 0, stream>>>(Y2, tokrow, topk_g, out);
}

// Round 4
// 520.307 us; speedup vs baseline: 1.4918x; 1.4918x over previous
//
#include <hip/hip_runtime.h>
#include <hip/hip_bf16.h>
#include <math.h>

namespace {

constexpr int NTOK   = 4096;   // B*T
constexpr int DDIM   = 1024;
constexpr int E      = 8;
constexpr int HDIM   = 2048;
constexpr int MAXROWS = 8192;  // NTOK * K (every token -> exactly 2 rows)
constexpr int MAXBLK  = 72;    // >= sum_e ceil(cnt_e/128) <= 64+7

typedef __bf16 bf16;
typedef __attribute__((ext_vector_type(4))) __bf16 bf16x4;
typedef __attribute__((ext_vector_type(8))) __bf16 bf16x8;
typedef __attribute__((ext_vector_type(4))) float floatx4;

// async global->LDS, 16B per lane; LDS dest = wave-uniform base + lane*16
__device__ inline void gload_lds16(const bf16* g, bf16* l) {
  __builtin_amdgcn_global_load_lds(
      (const __attribute__((address_space(1))) void*)g,
      (__attribute__((address_space(3))) void*)l, 16, 0, 0);
}

// ---------------- init ----------------
__global__ void init_kernel(int* counts) {
  if (threadIdx.x < E) counts[threadIdx.x] = 0;
}

// ------- router: fp32 logits -> top2 + gates; also writes bf16 cast of x -------
__global__ void router_kernel(const float* __restrict__ x,
                              const float* __restrict__ Wr,
                              const float* __restrict__ br,
                              int* __restrict__ counts,
                              int* __restrict__ topk_e,
                              float* __restrict__ topk_g,
                              bf16* __restrict__ xb) {
  int wave = threadIdx.x >> 6;
  int lane = threadIdx.x & 63;
  int t = blockIdx.x * 4 + wave;   // grid = NTOK/4, exact
  const float* xr = x + (size_t)t * DDIM;
  bf16* xbr = xb + (size_t)t * DDIM;

  float acc[E];
#pragma unroll
  for (int e = 0; e < E; ++e) acc[e] = 0.f;

#pragma unroll
  for (int i = 0; i < DDIM / 256; ++i) {
    int d0 = i * 256 + lane * 4;
    float4 xv = *(const float4*)(xr + d0);
    float xa[4];
    *(float4*)xa = xv;
    bf16x4 xc;
    xc[0] = (bf16)xv.x; xc[1] = (bf16)xv.y; xc[2] = (bf16)xv.z; xc[3] = (bf16)xv.w;
    *(bf16x4*)(xbr + d0) = xc;      // fused fp32->bf16 cast of x
#pragma unroll
    for (int j = 0; j < 4; ++j) {
      float xs = xa[j];
      float4 w0 = *(const float4*)(Wr + (size_t)(d0 + j) * E);
      float4 w1 = *(const float4*)(Wr + (size_t)(d0 + j) * E + 4);
      acc[0] += xs * w0.x; acc[1] += xs * w0.y;
      acc[2] += xs * w0.z; acc[3] += xs * w0.w;
      acc[4] += xs * w1.x; acc[5] += xs * w1.y;
      acc[6] += xs * w1.z; acc[7] += xs * w1.w;
    }
  }
#pragma unroll
  for (int off = 32; off > 0; off >>= 1) {
#pragma unroll
    for (int e = 0; e < E; ++e) acc[e] += __shfl_xor(acc[e], off, 64);
  }
  if (lane == 0) {
    float lg[E];
#pragma unroll
    for (int e = 0; e < E; ++e) lg[e] = acc[e] + br[e];
    int e0 = 0;
#pragma unroll
    for (int e = 1; e < E; ++e) if (lg[e] > lg[e0]) e0 = e;
    int e1 = (e0 == 0) ? 1 : 0;
#pragma unroll
    for (int e = 0; e < E; ++e) if (e != e0 && lg[e] > lg[e1]) e1 = e;
    float ex = expf(lg[e1] - lg[e0]);
    float s = 1.f + ex;
    topk_e[2 * t]     = e0;
    topk_e[2 * t + 1] = e1;
    topk_g[2 * t]     = 1.f / s;
    topk_g[2 * t + 1] = ex / s;
    atomicAdd(&counts[e0], 1);
    atomicAdd(&counts[e1], 1);
  }
}

// ------- scan: offsets + cursors + COMPACT BLOCK MAP (kills ghost blocks) -------
__global__ void scan_kernel(const int* __restrict__ counts,
                            int* __restrict__ offsets,
                            int* __restrict__ cursor,
                            int* __restrict__ blockmap,   // [MAXBLK] packed e<<16|mtile
                            int* __restrict__ nblk) {
  if (threadIdx.x == 0 && blockIdx.x == 0) {
    int s = 0, nb = 0;
    for (int e = 0; e < E; ++e) {
      offsets[e] = s; cursor[e] = s;
      int c = counts[e];
      int nt = (c + 127) >> 7;
      for (int m = 0; m < nt; ++m) blockmap[nb++] = (e << 16) | m;
      s += c;
    }
    offsets[E] = s;
    nblk[0] = nb;
  }
}

// ---------------- scatter: build permuted row space ----------------
__global__ void scatter_kernel(const int* __restrict__ topk_e,
                               int* __restrict__ cursor,
                               int* __restrict__ rowtok,
                               int* __restrict__ tokrow) {
  int t = blockIdx.x * 256 + threadIdx.x;   // grid = NTOK/256, exact
#pragma unroll
  for (int k = 0; k < 2; ++k) {
    int e = topk_e[2 * t + k];
    int row = atomicAdd(&cursor[e], 1);
    rowtok[row] = t;
    tokrow[2 * t + k] = row;
  }
}

// -------- batched transpose+cast: fp32 in [batch][R][C] -> bf16 out [batch][C][R] --------
__global__ void transpose_cast_kernel(const float* __restrict__ in, bf16* __restrict__ out,
                                      int R, int C) {
  __shared__ bf16 tile[64][72];
  const float* src = in + (size_t)blockIdx.z * R * C;
  bf16* dst = out + (size_t)blockIdx.z * R * C;
  int c0 = blockIdx.x * 64, r0 = blockIdx.y * 64;
  int tr = threadIdx.x >> 4;          // 0..15
  int tc = (threadIdx.x & 15) * 4;    // 0..60
#pragma unroll
  for (int i = 0; i < 4; ++i) {
    int r = tr + i * 16;
    float4 v = *(const float4*)(src + (size_t)(r0 + r) * C + c0 + tc);
    bf16x4 o;
    o[0] = (bf16)v.x; o[1] = (bf16)v.y; o[2] = (bf16)v.z; o[3] = (bf16)v.w;
    *(bf16x4*)&tile[r][tc] = o;
  }
  __syncthreads();
  int tr2 = threadIdx.x >> 3;         // 0..31
  int tc2 = (threadIdx.x & 7) * 8;    // 0..56
#pragma unroll
  for (int i = 0; i < 2; ++i) {
    int c = tr2 + i * 32;
    bf16x8 v;
#pragma unroll
    for (int j = 0; j < 8; ++j) v[j] = tile[tc2 + j][c];
    *(bf16x8*)(dst + (size_t)(c0 + c) * R + r0 + tc2) = v;
  }
}

// -------- grouped FFN GEMM (m97 structure, compact grid via blockmap) --------
// Y[row, n] = act( A_row . W[e][n][:] + bias[e][n] )
// A rows (bf16): GATHER ? X[rowtok[row]] : A[row]   (K-contiguous)
// W (bf16): [E][Ndim][Kdim]  (pre-transposed, K contiguous); bias fp32 [E][Ndim]
template <bool GATHER, bool RELU>
__global__ __launch_bounds__(256) void ffn_gemm(
    const bf16* __restrict__ A, const bf16* __restrict__ W,
    const float* __restrict__ bias, bf16* __restrict__ Y,
    const int* __restrict__ rowtok, const int* __restrict__ offsets,
    const int* __restrict__ counts,
    const int* __restrict__ blockmap, const int* __restrict__ nblk,
    int Kdim, int Ndim) {
  if ((int)blockIdx.x >= nblk[0]) return;   // <=8 ghosts, at tail of dispatch order
  int bm = blockmap[blockIdx.x];
  int e = bm >> 16;
  int mBase = (bm & 0xffff) << 7;
  int cnt = counts[e];
  int rowBase = offsets[e] + mBase;
  int nBase = blockIdx.y * 128;
  int validRows = cnt - mBase; if (validRows > 128) validRows = 128;

  // unpadded: layout must match global_load_lds lane order (base + lane*16)
  __shared__ bf16 Asm[128 * 64];
  __shared__ bf16 Bsm[128 * 64];

  int tid = threadIdx.x;
  int wave = tid >> 6, lane = tid & 63;
  int lrow = lane >> 3;     // 0..7  row within 8-row chunk
  int lseg = lane & 7;      // 16B segment within 128B row

  // staging pointers: chunk c = wave + i*4 covers rows [c*8, c*8+8)
  const bf16* aptr[4];
  const bf16* bptr[4];
#pragma unroll
  for (int i = 0; i < 4; ++i) {
    int c = wave + i * 4;
    int r = rowBase + c * 8 + lrow;
    if (r > MAXROWS - 1) r = MAXROWS - 1;   // partial tile: harmless dup, masked at store
    size_t rowoff = GATHER ? (size_t)rowtok[r] * Kdim : (size_t)r * Kdim;
    aptr[i] = A + rowoff + lseg * 8;
    bptr[i] = W + ((size_t)e * Ndim + nBase + c * 8 + lrow) * (size_t)Kdim + lseg * 8;
  }

  floatx4 acc[4][4];
#pragma unroll
  for (int m = 0; m < 4; ++m)
#pragma unroll
    for (int n = 0; n < 4; ++n) acc[m][n] = floatx4{0.f, 0.f, 0.f, 0.f};

  int wm = wave & 1, wn = wave >> 1;        // 2x2 wave grid, each wave 64x64
  int mrow = lane & 15;
  int kgrp = (lane >> 4) * 8;

  for (int kc = 0; kc < Kdim; kc += 64) {
#pragma unroll
    for (int i = 0; i < 4; ++i) {
      int c = wave + i * 4;
      gload_lds16(aptr[i] + kc, Asm + c * 512);
      gload_lds16(bptr[i] + kc, Bsm + c * 512);
    }
    __syncthreads();   // drains vmcnt -> LDS tiles complete & visible
#pragma unroll
    for (int ks = 0; ks < 2; ++ks) {
      int k0 = ks * 32 + kgrp;
      bf16x8 af[4], bf[4];
#pragma unroll
      for (int m = 0; m < 4; ++m)
        af[m] = *(const bf16x8*)&Asm[(wm * 64 + m * 16 + mrow) * 64 + k0];
#pragma unroll
      for (int n = 0; n < 4; ++n)
        bf[n] = *(const bf16x8*)&Bsm[(wn * 64 + n * 16 + mrow) * 64 + k0];
#pragma unroll
      for (int m = 0; m < 4; ++m)
#pragma unroll
        for (int n = 0; n < 4; ++n)
          acc[m][n] = __builtin_amdgcn_mfma_f32_16x16x32_bf16(af[m], bf[n], acc[m][n], 0, 0, 0);
    }
    __syncthreads();   // all frag reads done before next iter's overwrite
  }

  // epilogue: C/D layout col=lane&15, row=(lane>>4)*4+reg  [m89-verified]
  int crow = (lane >> 4) * 4;
  int ccol = lane & 15;
#pragma unroll
  for (int n = 0; n < 4; ++n) {
    int colg = nBase + wn * 64 + n * 16 + ccol;
    float bv = bias[(size_t)e * Ndim + colg];
#pragma unroll
    for (int m = 0; m < 4; ++m) {
#pragma unroll
      for (int r = 0; r < 4; ++r) {
        int rl = wm * 64 + m * 16 + crow + r;
        if (rl < validRows) {
          float v = acc[m][n][r] + bv;
          if (RELU) v = fmaxf(v, 0.f);
          Y[(size_t)(rowBase + rl) * Ndim + colg] = (bf16)v;
        }
      }
    }
  }
}

// ---------------- combine: out[t] = g0*Y2[r0] + g1*Y2[r1]  (fp32 out) ----------------
__global__ void combine_kernel(const bf16* __restrict__ Y2,
                               const int* __restrict__ tokrow,
                               const float* __restrict__ topk_g,
                               float* __restrict__ out) {
  int idx = blockIdx.x * 256 + threadIdx.x;
  int t = idx >> 7;              // DDIM/8 = 128 vectors per token
  int d8 = (idx & 127) * 8;
  int r0 = tokrow[2 * t], r1 = tokrow[2 * t + 1];
  float g0 = topk_g[2 * t], g1 = topk_g[2 * t + 1];
  bf16x8 a = *(const bf16x8*)(Y2 + (size_t)r0 * DDIM + d8);
  bf16x8 b = *(const bf16x8*)(Y2 + (size_t)r1 * DDIM + d8);
  float o[8];
#pragma unroll
  for (int j = 0; j < 8; ++j) o[j] = g0 * (float)a[j] + g1 * (float)b[j];
  float* op = out + (size_t)t * DDIM + d8;
  *(float4*)op = *(float4*)&o[0];
  *(float4*)(op + 4) = *(float4*)&o[4];
}

}  // namespace

extern "C" void kernel_launch(void* const* d_in, const int* in_sizes, int n_in,
                              void* d_out, int out_size, void* d_ws, size_t ws_size,
                              hipStream_t stream) {
  const float* x  = (const float*)d_in[0];   // [B,T,D] fp32
  const float* Wr = (const float*)d_in[1];   // [D,E]   fp32
  const float* br = (const float*)d_in[2];   // [E]     fp32
  const float* W1 = (const float*)d_in[3];   // [E,D,H] fp32
  const float* b1 = (const float*)d_in[4];   // [E,H]   fp32
  const float* W2 = (const float*)d_in[5];   // [E,H,D] fp32
  const float* b2 = (const float*)d_in[6];   // [E,D]   fp32
  float* out = (float*)d_out;                // [B,T,D] fp32

  char* w = (char*)d_ws;
  int*   counts   = (int*)(w);
  int*   offsets  = (int*)(w + 256);
  int*   cursor   = (int*)(w + 512);
  int*   blockmap = (int*)(w + 768);         // 72 ints
  int*   nblk     = (int*)(w + 768 + 512);
  int*   topk_e   = (int*)(w + 2048);
  float* topk_g   = (float*)(w + 2048 + 32768);
  int*   rowtok   = (int*)(w + 2048 + 65536);
  int*   tokrow   = (int*)(w + 2048 + 98304);
  char*  big      = w + 2048 + 131072;
  bf16* xb  = (bf16*)(big);                        // [4096][D]  bf16   8.4 MB
  bf16* W1T = (bf16*)(big + 8388608);              // [E][H][D]  bf16  33.5 MB
  bf16* W2T = (bf16*)(big + 8388608 + 33554432);   // [E][D][H]  bf16  33.5 MB
  bf16* Y1  = (bf16*)(big + 8388608 + 67108864);   // [8192][H]  bf16  33.5 MB
  bf16* Y2  = (bf16*)(big + 8388608);              // alias W1T (dead after GEMM1)

  init_kernel<<<1, 64, 0, stream>>>(counts);
  transpose_cast_kernel<<<dim3(HDIM / 64, DDIM / 64, E), 256, 0, stream>>>(W1, W1T, DDIM, HDIM);
  transpose_cast_kernel<<<dim3(DDIM / 64, HDIM / 64, E), 256, 0, stream>>>(W2, W2T, HDIM, DDIM);
  router_kernel<<<NTOK / 4, 256, 0, stream>>>(x, Wr, br, counts, topk_e, topk_g, xb);
  scan_kernel<<<1, 1, 0, stream>>>(counts, offsets, cursor, blockmap, nblk);
  scatter_kernel<<<NTOK / 256, 256, 0, stream>>>(topk_e, cursor, rowtok, tokrow);
  ffn_gemm<true, true><<<dim3(MAXBLK, HDIM / 128), 256, 0, stream>>>(
      xb, W1T, b1, Y1, rowtok, offsets, counts, blockmap, nblk, DDIM, HDIM);
  ffn_gemm<false, false><<<dim3(MAXBLK, DDIM / 128), 256, 0, stream>>>(
      Y1, W2T, b2, Y2, rowtok, offsets, counts, blockmap, nblk, HDIM, DDIM);
  combine_kernel<<<NTOK * DDIM / 8 / 256, 256, 0, stream>>>(Y2, tokrow, topk_g, out);
}

// Round 5
// 512.795 us; speedup vs baseline: 1.5136x; 1.0146x over previous
//
#include <hip/hip_runtime.h>
#include <hip/hip_bf16.h>
#include <math.h>

namespace {

constexpr int NTOK   = 4096;   // B*T
constexpr int DDIM   = 1024;
constexpr int E      = 8;
constexpr int HDIM   = 2048;
constexpr int MAXROWS = 8192;  // NTOK * K (every token -> exactly 2 rows)
constexpr int MAXBLK  = 72;    // >= sum_e ceil(cnt_e/128) <= 64+7

typedef __bf16 bf16;
typedef __attribute__((ext_vector_type(4))) __bf16 bf16x4;
typedef __attribute__((ext_vector_type(8))) __bf16 bf16x8;
typedef __attribute__((ext_vector_type(4))) float floatx4;

// async global->LDS, 16B per lane; LDS dest = wave-uniform base + lane*16
__device__ inline void gload_lds16(const bf16* g, bf16* l) {
  __builtin_amdgcn_global_load_lds(
      (const __attribute__((address_space(1))) void*)g,
      (__attribute__((address_space(3))) void*)l, 16, 0, 0);
}

// ---------------- init ----------------
__global__ void init_kernel(int* counts) {
  if (threadIdx.x < E) counts[threadIdx.x] = 0;
}

// ------- router: fp32 logits -> top2 + gates; also writes bf16 cast of x -------
__global__ void router_kernel(const float* __restrict__ x,
                              const float* __restrict__ Wr,
                              const float* __restrict__ br,
                              int* __restrict__ counts,
                              int* __restrict__ topk_e,
                              float* __restrict__ topk_g,
                              bf16* __restrict__ xb) {
  int wave = threadIdx.x >> 6;
  int lane = threadIdx.x & 63;
  int t = blockIdx.x * 4 + wave;   // grid = NTOK/4, exact
  const float* xr = x + (size_t)t * DDIM;
  bf16* xbr = xb + (size_t)t * DDIM;

  float acc[E];
#pragma unroll
  for (int e = 0; e < E; ++e) acc[e] = 0.f;

#pragma unroll
  for (int i = 0; i < DDIM / 256; ++i) {
    int d0 = i * 256 + lane * 4;
    float4 xv = *(const float4*)(xr + d0);
    float xa[4];
    *(float4*)xa = xv;
    bf16x4 xc;
    xc[0] = (bf16)xv.x; xc[1] = (bf16)xv.y; xc[2] = (bf16)xv.z; xc[3] = (bf16)xv.w;
    *(bf16x4*)(xbr + d0) = xc;      // fused fp32->bf16 cast of x
#pragma unroll
    for (int j = 0; j < 4; ++j) {
      float xs = xa[j];
      float4 w0 = *(const float4*)(Wr + (size_t)(d0 + j) * E);
      float4 w1 = *(const float4*)(Wr + (size_t)(d0 + j) * E + 4);
      acc[0] += xs * w0.x; acc[1] += xs * w0.y;
      acc[2] += xs * w0.z; acc[3] += xs * w0.w;
      acc[4] += xs * w1.x; acc[5] += xs * w1.y;
      acc[6] += xs * w1.z; acc[7] += xs * w1.w;
    }
  }
#pragma unroll
  for (int off = 32; off > 0; off >>= 1) {
#pragma unroll
    for (int e = 0; e < E; ++e) acc[e] += __shfl_xor(acc[e], off, 64);
  }
  if (lane == 0) {
    float lg[E];
#pragma unroll
    for (int e = 0; e < E; ++e) lg[e] = acc[e] + br[e];
    int e0 = 0;
#pragma unroll
    for (int e = 1; e < E; ++e) if (lg[e] > lg[e0]) e0 = e;
    int e1 = (e0 == 0) ? 1 : 0;
#pragma unroll
    for (int e = 0; e < E; ++e) if (e != e0 && lg[e] > lg[e1]) e1 = e;
    float ex = expf(lg[e1] - lg[e0]);
    float s = 1.f + ex;
    topk_e[2 * t]     = e0;
    topk_e[2 * t + 1] = e1;
    topk_g[2 * t]     = 1.f / s;
    topk_g[2 * t + 1] = ex / s;
    atomicAdd(&counts[e0], 1);
    atomicAdd(&counts[e1], 1);
  }
}

// ------- scan: offsets + cursors + compact block map -------
__global__ void scan_kernel(const int* __restrict__ counts,
                            int* __restrict__ offsets,
                            int* __restrict__ cursor,
                            int* __restrict__ blockmap,   // [MAXBLK] packed e<<16|mtile
                            int* __restrict__ nblk) {
  if (threadIdx.x == 0 && blockIdx.x == 0) {
    int s = 0, nb = 0;
    for (int e = 0; e < E; ++e) {
      offsets[e] = s; cursor[e] = s;
      int c = counts[e];
      int nt = (c + 127) >> 7;
      for (int m = 0; m < nt; ++m) blockmap[nb++] = (e << 16) | m;
      s += c;
    }
    offsets[E] = s;
    nblk[0] = nb;
  }
}

// ---------------- scatter: build permuted row space ----------------
__global__ void scatter_kernel(const int* __restrict__ topk_e,
                               int* __restrict__ cursor,
                               int* __restrict__ rowtok,
                               int* __restrict__ tokrow) {
  int t = blockIdx.x * 256 + threadIdx.x;   // grid = NTOK/256, exact
#pragma unroll
  for (int k = 0; k < 2; ++k) {
    int e = topk_e[2 * t + k];
    int row = atomicAdd(&cursor[e], 1);
    rowtok[row] = t;
    tokrow[2 * t + k] = row;
  }
}

// -------- batched transpose+cast: fp32 in [batch][R][C] -> bf16 out [batch][C][R] --------
__global__ void transpose_cast_kernel(const float* __restrict__ in, bf16* __restrict__ out,
                                      int R, int C) {
  __shared__ bf16 tile[64][72];
  const float* src = in + (size_t)blockIdx.z * R * C;
  bf16* dst = out + (size_t)blockIdx.z * R * C;
  int c0 = blockIdx.x * 64, r0 = blockIdx.y * 64;
  int tr = threadIdx.x >> 4;          // 0..15
  int tc = (threadIdx.x & 15) * 4;    // 0..60
#pragma unroll
  for (int i = 0; i < 4; ++i) {
    int r = tr + i * 16;
    float4 v = *(const float4*)(src + (size_t)(r0 + r) * C + c0 + tc);
    bf16x4 o;
    o[0] = (bf16)v.x; o[1] = (bf16)v.y; o[2] = (bf16)v.z; o[3] = (bf16)v.w;
    *(bf16x4*)&tile[r][tc] = o;
  }
  __syncthreads();
  int tr2 = threadIdx.x >> 3;         // 0..31
  int tc2 = (threadIdx.x & 7) * 8;    // 0..56
#pragma unroll
  for (int i = 0; i < 2; ++i) {
    int c = tr2 + i * 32;
    bf16x8 v;
#pragma unroll
    for (int j = 0; j < 8; ++j) v[j] = tile[tc2 + j][c];
    *(bf16x8*)(dst + (size_t)(c0 + c) * R + r0 + tc2) = v;
  }
}

// -------- grouped FFN GEMM: compact grid + double-buffered async-LDS pipeline --------
// Y[row, n] = act( A_row . W[e][n][:] + bias[e][n] )
// A rows (bf16): GATHER ? X[rowtok[row]] : A[row]   (K-contiguous)
// W (bf16): [E][Ndim][Kdim]  (pre-transposed, K contiguous); bias fp32 [E][Ndim]
template <bool GATHER, bool RELU>
__global__ __launch_bounds__(256) void ffn_gemm(
    const bf16* __restrict__ A, const bf16* __restrict__ W,
    const float* __restrict__ bias, bf16* __restrict__ Y,
    const int* __restrict__ rowtok, const int* __restrict__ offsets,
    const int* __restrict__ counts,
    const int* __restrict__ blockmap, const int* __restrict__ nblk,
    int Kdim, int Ndim) {
  if ((int)blockIdx.x >= nblk[0]) return;   // <=8 ghosts, tail of dispatch order
  int bm = blockmap[blockIdx.x];
  int e = bm >> 16;
  int mBase = (bm & 0xffff) << 7;
  int cnt = counts[e];
  int rowBase = offsets[e] + mBase;
  int nBase = blockIdx.y * 128;
  int validRows = cnt - mBase; if (validRows > 128) validRows = 128;

  // double-buffered; unpadded: layout must match global_load_lds lane order
  __shared__ bf16 Asm[2][128 * 64];
  __shared__ bf16 Bsm[2][128 * 64];

  int tid = threadIdx.x;
  int wave = tid >> 6, lane = tid & 63;
  int lrow = lane >> 3;     // 0..7  row within 8-row chunk
  int lseg = lane & 7;      // 16B segment within 128B row

  // staging pointers: chunk c = wave + i*4 covers rows [c*8, c*8+8)
  const bf16* aptr[4];
  const bf16* bptr[4];
#pragma unroll
  for (int i = 0; i < 4; ++i) {
    int c = wave + i * 4;
    int r = rowBase + c * 8 + lrow;
    if (r > MAXROWS - 1) r = MAXROWS - 1;   // partial tile: harmless dup, masked at store
    size_t rowoff = GATHER ? (size_t)rowtok[r] * Kdim : (size_t)r * Kdim;
    aptr[i] = A + rowoff + lseg * 8;
    bptr[i] = W + ((size_t)e * Ndim + nBase + c * 8 + lrow) * (size_t)Kdim + lseg * 8;
  }

  floatx4 acc[4][4];
#pragma unroll
  for (int m = 0; m < 4; ++m)
#pragma unroll
    for (int n = 0; n < 4; ++n) acc[m][n] = floatx4{0.f, 0.f, 0.f, 0.f};

  int wm = wave & 1, wn = wave >> 1;        // 2x2 wave grid, each wave 64x64
  int mrow = lane & 15;
  int kgrp = (lane >> 4) * 8;

  // issue 8 async loads (4 A + 4 B) for k-chunk kc into buffer p
  auto issue = [&](int p, int kc) {
#pragma unroll
    for (int i = 0; i < 4; ++i) {
      int c = wave + i * 4;
      gload_lds16(aptr[i] + kc, &Asm[p][c * 512]);
      gload_lds16(bptr[i] + kc, &Bsm[p][c * 512]);
    }
  };

  issue(0, 0);                 // preload
  int p = 0;
  for (int kc = 0; kc < Kdim; kc += 64) {
    if (kc + 64 < Kdim) {
      issue(p ^ 1, kc + 64);   // prefetch next chunk into other buffer
      // wait only the OLDER 8 loads (buffer p); the 8 just issued stay in flight
      asm volatile("s_waitcnt vmcnt(8)" ::: "memory");
    } else {
      asm volatile("s_waitcnt vmcnt(0)" ::: "memory");
    }
    asm volatile("s_barrier" ::: "memory");   // buf p complete for all waves
#pragma unroll
    for (int ks = 0; ks < 2; ++ks) {
      int k0 = ks * 32 + kgrp;
      bf16x8 af[4], bf[4];
#pragma unroll
      for (int m = 0; m < 4; ++m)
        af[m] = *(const bf16x8*)&Asm[p][(wm * 64 + m * 16 + mrow) * 64 + k0];
#pragma unroll
      for (int n = 0; n < 4; ++n)
        bf[n] = *(const bf16x8*)&Bsm[p][(wn * 64 + n * 16 + mrow) * 64 + k0];
#pragma unroll
      for (int m = 0; m < 4; ++m)
#pragma unroll
        for (int n = 0; n < 4; ++n)
          acc[m][n] = __builtin_amdgcn_mfma_f32_16x16x32_bf16(af[m], bf[n], acc[m][n], 0, 0, 0);
    }
    // all waves done reading buf p before next iter's issue overwrites it
    asm volatile("s_waitcnt lgkmcnt(0)\n\ts_barrier" ::: "memory");
    p ^= 1;
  }

  // epilogue: C/D layout col=lane&15, row=(lane>>4)*4+reg  [m89-verified]
  int crow = (lane >> 4) * 4;
  int ccol = lane & 15;
#pragma unroll
  for (int n = 0; n < 4; ++n) {
    int colg = nBase + wn * 64 + n * 16 + ccol;
    float bv = bias[(size_t)e * Ndim + colg];
#pragma unroll
    for (int m = 0; m < 4; ++m) {
#pragma unroll
      for (int r = 0; r < 4; ++r) {
        int rl = wm * 64 + m * 16 + crow + r;
        if (rl < validRows) {
          float v = acc[m][n][r] + bv;
          if (RELU) v = fmaxf(v, 0.f);
          Y[(size_t)(rowBase + rl) * Ndim + colg] = (bf16)v;
        }
      }
    }
  }
}

// ---------------- combine: out[t] = g0*Y2[r0] + g1*Y2[r1]  (fp32 out) ----------------
__global__ void combine_kernel(const bf16* __restrict__ Y2,
                               const int* __restrict__ tokrow,
                               const float* __restrict__ topk_g,
                               float* __restrict__ out) {
  int idx = blockIdx.x * 256 + threadIdx.x;
  int t = idx >> 7;              // DDIM/8 = 128 vectors per token
  int d8 = (idx & 127) * 8;
  int r0 = tokrow[2 * t], r1 = tokrow[2 * t + 1];
  float g0 = topk_g[2 * t], g1 = topk_g[2 * t + 1];
  bf16x8 a = *(const bf16x8*)(Y2 + (size_t)r0 * DDIM + d8);
  bf16x8 b = *(const bf16x8*)(Y2 + (size_t)r1 * DDIM + d8);
  float o[8];
#pragma unroll
  for (int j = 0; j < 8; ++j) o[j] = g0 * (float)a[j] + g1 * (float)b[j];
  float* op = out + (size_t)t * DDIM + d8;
  *(float4*)op = *(float4*)&o[0];
  *(float4*)(op + 4) = *(float4*)&o[4];
}

}  // namespace

extern "C" void kernel_launch(void* const* d_in, const int* in_sizes, int n_in,
                              void* d_out, int out_size, void* d_ws, size_t ws_size,
                              hipStream_t stream) {
  const float* x  = (const float*)d_in[0];   // [B,T,D] fp32
  const float* Wr = (const float*)d_in[1];   // [D,E]   fp32
  const float* br = (const float*)d_in[2];   // [E]     fp32
  const float* W1 = (const float*)d_in[3];   // [E,D,H] fp32
  const float* b1 = (const float*)d_in[4];   // [E,H]   fp32
  const float* W2 = (const float*)d_in[5];   // [E,H,D] fp32
  const float* b2 = (const float*)d_in[6];   // [E,D]   fp32
  float* out = (float*)d_out;                // [B,T,D] fp32

  char* w = (char*)d_ws;
  int*   counts   = (int*)(w);
  int*   offsets  = (int*)(w + 256);
  int*   cursor   = (int*)(w + 512);
  int*   blockmap = (int*)(w + 768);         // 72 ints
  int*   nblk     = (int*)(w + 768 + 512);
  int*   topk_e   = (int*)(w + 2048);
  float* topk_g   = (float*)(w + 2048 + 32768);
  int*   rowtok   = (int*)(w + 2048 + 65536);
  int*   tokrow   = (int*)(w + 2048 + 98304);
  char*  big      = w + 2048 + 131072;
  bf16* xb  = (bf16*)(big);                        // [4096][D]  bf16   8.4 MB
  bf16* W1T = (bf16*)(big + 8388608);              // [E][H][D]  bf16  33.5 MB
  bf16* W2T = (bf16*)(big + 8388608 + 33554432);   // [E][D][H]  bf16  33.5 MB
  bf16* Y1  = (bf16*)(big + 8388608 + 67108864);   // [8192][H]  bf16  33.5 MB
  bf16* Y2  = (bf16*)(big + 8388608);              // alias W1T (dead after GEMM1)

  init_kernel<<<1, 64, 0, stream>>>(counts);
  transpose_cast_kernel<<<dim3(HDIM / 64, DDIM / 64, E), 256, 0, stream>>>(W1, W1T, DDIM, HDIM);
  transpose_cast_kernel<<<dim3(DDIM / 64, HDIM / 64, E), 256, 0, stream>>>(W2, W2T, HDIM, DDIM);
  router_kernel<<<NTOK / 4, 256, 0, stream>>>(x, Wr, br, counts, topk_e, topk_g, xb);
  scan_kernel<<<1, 1, 0, stream>>>(counts, offsets, cursor, blockmap, nblk);
  scatter_kernel<<<NTOK / 256, 256, 0, stream>>>(topk_e, cursor, rowtok, tokrow);
  ffn_gemm<true, true><<<dim3(MAXBLK, HDIM / 128), 256, 0, stream>>>(
      xb, W1T, b1, Y1, rowtok, offsets, counts, blockmap, nblk, DDIM, HDIM);
  ffn_gemm<false, false><<<dim3(MAXBLK, DDIM / 128), 256, 0, stream>>>(
      Y1, W2T, b2, Y2, rowtok, offsets, counts, blockmap, nblk, HDIM, DDIM);
  combine_kernel<<<NTOK * DDIM / 8 / 256, 256, 0, stream>>>(Y2, tokrow, topk_g, out);
}

// Round 6
// 418.857 us; speedup vs baseline: 1.8531x; 1.2243x over previous
//
#include <hip/hip_runtime.h>
#include <hip/hip_bf16.h>
#include <math.h>

namespace {

constexpr int NTOK   = 4096;   // B*T
constexpr int DDIM   = 1024;
constexpr int E      = 8;
constexpr int HDIM   = 2048;
constexpr int MAXROWS = 8192;  // NTOK * K (every token -> exactly 2 rows)
constexpr int MAXBLK  = 72;    // >= sum_e ceil(cnt_e/128) <= 64+7

typedef __bf16 bf16;
typedef __attribute__((ext_vector_type(4))) __bf16 bf16x4;
typedef __attribute__((ext_vector_type(8))) __bf16 bf16x8;
typedef __attribute__((ext_vector_type(4))) float floatx4;

// async global->LDS, 16B per lane; LDS dest = wave-uniform base + lane*16
__device__ inline void gload_lds16(const bf16* g, bf16* l) {
  __builtin_amdgcn_global_load_lds(
      (const __attribute__((address_space(1))) void*)g,
      (__attribute__((address_space(3))) void*)l, 16, 0, 0);
}

// ---------------- init: zero strided counts region (128 ints = 512B) ----------------
__global__ void init_kernel(int* counts) {
  counts[threadIdx.x] = 0;   // 128 threads
}

// ------- router: fp32 logits -> top2 + gates; fused bf16 cast of x -------
// wave = 2 tokens; lane l owns channels d = l + 64*i  (coalesced x, 32B-stride Wr)
__global__ void router_kernel(const float* __restrict__ x,
                              const float* __restrict__ Wr,
                              const float* __restrict__ br,
                              int* __restrict__ counts,     // stride 16 ints per expert
                              int* __restrict__ topk_e,
                              float* __restrict__ topk_g,
                              bf16* __restrict__ xb) {
  int wave = threadIdx.x >> 6;
  int lane = threadIdx.x & 63;
  int t0 = (blockIdx.x * 4 + wave) * 2;   // grid = NTOK/8, exact

  float acc[16];
#pragma unroll
  for (int j = 0; j < 16; ++j) acc[j] = 0.f;

#pragma unroll
  for (int i = 0; i < DDIM / 64; ++i) {
    int d = i * 64 + lane;
    float4 w0 = *(const float4*)(Wr + (size_t)d * E);
    float4 w1 = *(const float4*)(Wr + (size_t)d * E + 4);
#pragma unroll
    for (int t = 0; t < 2; ++t) {
      float xv = x[(size_t)(t0 + t) * DDIM + d];
      xb[(size_t)(t0 + t) * DDIM + d] = (bf16)xv;
      acc[t * 8 + 0] += xv * w0.x; acc[t * 8 + 1] += xv * w0.y;
      acc[t * 8 + 2] += xv * w0.z; acc[t * 8 + 3] += xv * w0.w;
      acc[t * 8 + 4] += xv * w1.x; acc[t * 8 + 5] += xv * w1.y;
      acc[t * 8 + 6] += xv * w1.z; acc[t * 8 + 7] += xv * w1.w;
    }
  }
  // 64-lane butterfly: every lane ends with the full sums
#pragma unroll
  for (int off = 32; off > 0; off >>= 1) {
#pragma unroll
    for (int j = 0; j < 16; ++j) acc[j] += __shfl_xor(acc[j], off, 64);
  }
  if (lane == 0) {
#pragma unroll
    for (int t = 0; t < 2; ++t) {
      int tt = t0 + t;
      float lg[E];
#pragma unroll
      for (int e = 0; e < E; ++e) lg[e] = acc[t * 8 + e] + br[e];
      // top-1 then top-2; strict > keeps lowest index on ties (jax top_k order)
      int e0 = 0;
#pragma unroll
      for (int e = 1; e < E; ++e) if (lg[e] > lg[e0]) e0 = e;
      int e1 = (e0 == 0) ? 1 : 0;
#pragma unroll
      for (int e = 0; e < E; ++e) if (e != e0 && lg[e] > lg[e1]) e1 = e;
      float ex = expf(lg[e1] - lg[e0]);
      float s = 1.f + ex;
      topk_e[2 * tt]     = e0;
      topk_e[2 * tt + 1] = e1;
      topk_g[2 * tt]     = 1.f / s;
      topk_g[2 * tt + 1] = ex / s;
      atomicAdd(&counts[e0 * 16], 1);
      atomicAdd(&counts[e1 * 16], 1);
    }
  }
}

// ------- scan: offsets + cursors + compact block map -------
__global__ void scan_kernel(const int* __restrict__ counts,   // stride 16
                            int* __restrict__ offsets,
                            int* __restrict__ cursor,          // stride 16
                            int* __restrict__ blockmap,        // [MAXBLK] packed e<<16|mtile
                            int* __restrict__ nblk) {
  if (threadIdx.x == 0 && blockIdx.x == 0) {
    int s = 0, nb = 0;
    for (int e = 0; e < E; ++e) {
      offsets[e] = s; cursor[e * 16] = s;
      int c = counts[e * 16];
      int nt = (c + 127) >> 7;
      for (int m = 0; m < nt; ++m) blockmap[nb++] = (e << 16) | m;
      s += c;
    }
    offsets[E] = s;
    nblk[0] = nb;
  }
}

// ------- scatter: wave-aggregated cursor atomics (1 atomic per (e,k) per wave) -------
__global__ void scatter_kernel(const int* __restrict__ topk_e,
                               int* __restrict__ cursor,       // stride 16
                               int* __restrict__ rowtok,
                               int* __restrict__ tokrow) {
  int t = blockIdx.x * 256 + threadIdx.x;   // grid = NTOK/256, exact
  int lane = threadIdx.x & 63;
  unsigned long long lt = ((unsigned long long)1 << lane) - 1;
#pragma unroll
  for (int k = 0; k < 2; ++k) {
    int e = topk_e[2 * t + k];
#pragma unroll
    for (int ee = 0; ee < E; ++ee) {
      unsigned long long m = __ballot(e == ee);
      if (m) {
        int leader = __ffsll((long long)m) - 1;
        int base = 0;
        if (lane == leader) base = atomicAdd(&cursor[ee * 16], __popcll(m));
        base = __shfl(base, leader, 64);
        if (e == ee) {
          int row = base + __popcll(m & lt);
          rowtok[row] = t;
          tokrow[2 * t + k] = row;
        }
      }
    }
  }
}

// -------- batched transpose+cast: fp32 in [batch][R][C] -> bf16 out [batch][C][R] --------
__global__ void transpose_cast_kernel(const float* __restrict__ in, bf16* __restrict__ out,
                                      int R, int C) {
  __shared__ bf16 tile[64][72];
  const float* src = in + (size_t)blockIdx.z * R * C;
  bf16* dst = out + (size_t)blockIdx.z * R * C;
  int c0 = blockIdx.x * 64, r0 = blockIdx.y * 64;
  int tr = threadIdx.x >> 4;          // 0..15
  int tc = (threadIdx.x & 15) * 4;    // 0..60
#pragma unroll
  for (int i = 0; i < 4; ++i) {
    int r = tr + i * 16;
    float4 v = *(const float4*)(src + (size_t)(r0 + r) * C + c0 + tc);
    bf16x4 o;
    o[0] = (bf16)v.x; o[1] = (bf16)v.y; o[2] = (bf16)v.z; o[3] = (bf16)v.w;
    *(bf16x4*)&tile[r][tc] = o;
  }
  __syncthreads();
  int tr2 = threadIdx.x >> 3;         // 0..31
  int tc2 = (threadIdx.x & 7) * 8;    // 0..56
#pragma unroll
  for (int i = 0; i < 2; ++i) {
    int c = tr2 + i * 32;
    bf16x8 v;
#pragma unroll
    for (int j = 0; j < 8; ++j) v[j] = tile[tc2 + j][c];
    *(bf16x8*)(dst + (size_t)(c0 + c) * R + r0 + tc2) = v;
  }
}

// -------- grouped FFN GEMM: compact grid + double-buffered async-LDS pipeline --------
template <bool GATHER, bool RELU>
__global__ __launch_bounds__(256) void ffn_gemm(
    const bf16* __restrict__ A, const bf16* __restrict__ W,
    const float* __restrict__ bias, bf16* __restrict__ Y,
    const int* __restrict__ rowtok, const int* __restrict__ offsets,
    const int* __restrict__ counts,   // stride 16
    const int* __restrict__ blockmap, const int* __restrict__ nblk,
    int Kdim, int Ndim) {
  if ((int)blockIdx.x >= nblk[0]) return;   // <=8 ghosts, tail of dispatch order
  int bm = blockmap[blockIdx.x];
  int e = bm >> 16;
  int mBase = (bm & 0xffff) << 7;
  int cnt = counts[e * 16];
  int rowBase = offsets[e] + mBase;
  int nBase = blockIdx.y * 128;
  int validRows = cnt - mBase; if (validRows > 128) validRows = 128;

  __shared__ bf16 Asm[2][128 * 64];
  __shared__ bf16 Bsm[2][128 * 64];

  int tid = threadIdx.x;
  int wave = tid >> 6, lane = tid & 63;
  int lrow = lane >> 3;     // 0..7  row within 8-row chunk
  int lseg = lane & 7;      // 16B segment within 128B row

  const bf16* aptr[4];
  const bf16* bptr[4];
#pragma unroll
  for (int i = 0; i < 4; ++i) {
    int c = wave + i * 4;
    int r = rowBase + c * 8 + lrow;
    if (r > MAXROWS - 1) r = MAXROWS - 1;   // partial tile: harmless dup, masked at store
    size_t rowoff = GATHER ? (size_t)rowtok[r] * Kdim : (size_t)r * Kdim;
    aptr[i] = A + rowoff + lseg * 8;
    bptr[i] = W + ((size_t)e * Ndim + nBase + c * 8 + lrow) * (size_t)Kdim + lseg * 8;
  }

  floatx4 acc[4][4];
#pragma unroll
  for (int m = 0; m < 4; ++m)
#pragma unroll
    for (int n = 0; n < 4; ++n) acc[m][n] = floatx4{0.f, 0.f, 0.f, 0.f};

  int wm = wave & 1, wn = wave >> 1;        // 2x2 wave grid, each wave 64x64
  int mrow = lane & 15;
  int kgrp = (lane >> 4) * 8;

  auto issue = [&](int p, int kc) {
#pragma unroll
    for (int i = 0; i < 4; ++i) {
      int c = wave + i * 4;
      gload_lds16(aptr[i] + kc, &Asm[p][c * 512]);
      gload_lds16(bptr[i] + kc, &Bsm[p][c * 512]);
    }
  };

  issue(0, 0);
  int p = 0;
  for (int kc = 0; kc < Kdim; kc += 64) {
    if (kc + 64 < Kdim) {
      issue(p ^ 1, kc + 64);
      asm volatile("s_waitcnt vmcnt(8)" ::: "memory");
    } else {
      asm volatile("s_waitcnt vmcnt(0)" ::: "memory");
    }
    asm volatile("s_barrier" ::: "memory");
#pragma unroll
    for (int ks = 0; ks < 2; ++ks) {
      int k0 = ks * 32 + kgrp;
      bf16x8 af[4], bf[4];
#pragma unroll
      for (int m = 0; m < 4; ++m)
        af[m] = *(const bf16x8*)&Asm[p][(wm * 64 + m * 16 + mrow) * 64 + k0];
#pragma unroll
      for (int n = 0; n < 4; ++n)
        bf[n] = *(const bf16x8*)&Bsm[p][(wn * 64 + n * 16 + mrow) * 64 + k0];
#pragma unroll
      for (int m = 0; m < 4; ++m)
#pragma unroll
        for (int n = 0; n < 4; ++n)
          acc[m][n] = __builtin_amdgcn_mfma_f32_16x16x32_bf16(af[m], bf[n], acc[m][n], 0, 0, 0);
    }
    asm volatile("s_waitcnt lgkmcnt(0)\n\ts_barrier" ::: "memory");
    p ^= 1;
  }

  // epilogue: C/D layout col=lane&15, row=(lane>>4)*4+reg  [m89-verified]
  int crow = (lane >> 4) * 4;
  int ccol = lane & 15;
#pragma unroll
  for (int n = 0; n < 4; ++n) {
    int colg = nBase + wn * 64 + n * 16 + ccol;
    float bv = bias[(size_t)e * Ndim + colg];
#pragma unroll
    for (int m = 0; m < 4; ++m) {
#pragma unroll
      for (int r = 0; r < 4; ++r) {
        int rl = wm * 64 + m * 16 + crow + r;
        if (rl < validRows) {
          float v = acc[m][n][r] + bv;
          if (RELU) v = fmaxf(v, 0.f);
          Y[(size_t)(rowBase + rl) * Ndim + colg] = (bf16)v;
        }
      }
    }
  }
}

// ---------------- combine: out[t] = g0*Y2[r0] + g1*Y2[r1]  (fp32 out) ----------------
__global__ void combine_kernel(const bf16* __restrict__ Y2,
                               const int* __restrict__ tokrow,
                               const float* __restrict__ topk_g,
                               float* __restrict__ out) {
  int idx = blockIdx.x * 256 + threadIdx.x;
  int t = idx >> 7;              // DDIM/8 = 128 vectors per token
  int d8 = (idx & 127) * 8;
  int r0 = tokrow[2 * t], r1 = tokrow[2 * t + 1];
  float g0 = topk_g[2 * t], g1 = topk_g[2 * t + 1];
  bf16x8 a = *(const bf16x8*)(Y2 + (size_t)r0 * DDIM + d8);
  bf16x8 b = *(const bf16x8*)(Y2 + (size_t)r1 * DDIM + d8);
  float o[8];
#pragma unroll
  for (int j = 0; j < 8; ++j) o[j] = g0 * (float)a[j] + g1 * (float)b[j];
  float* op = out + (size_t)t * DDIM + d8;
  *(float4*)op = *(float4*)&o[0];
  *(float4*)(op + 4) = *(float4*)&o[4];
}

}  // namespace

extern "C" void kernel_launch(void* const* d_in, const int* in_sizes, int n_in,
                              void* d_out, int out_size, void* d_ws, size_t ws_size,
                              hipStream_t stream) {
  const float* x  = (const float*)d_in[0];   // [B,T,D] fp32
  const float* Wr = (const float*)d_in[1];   // [D,E]   fp32
  const float* br = (const float*)d_in[2];   // [E]     fp32
  const float* W1 = (const float*)d_in[3];   // [E,D,H] fp32
  const float* b1 = (const float*)d_in[4];   // [E,H]   fp32
  const float* W2 = (const float*)d_in[5];   // [E,H,D] fp32
  const float* b2 = (const float*)d_in[6];   // [E,D]   fp32
  float* out = (float*)d_out;                // [B,T,D] fp32

  char* w = (char*)d_ws;
  int*   counts   = (int*)(w);               // 8 experts, stride 16 ints (64B apart)
  int*   cursor   = (int*)(w + 512);         // 8 experts, stride 16 ints
  int*   offsets  = (int*)(w + 1024);        // 9 ints
  int*   blockmap = (int*)(w + 2048);        // 72 ints
  int*   nblk     = (int*)(w + 2048 + 512);
  int*   topk_e   = (int*)(w + 4096);
  float* topk_g   = (float*)(w + 4096 + 32768);
  int*   rowtok   = (int*)(w + 4096 + 65536);
  int*   tokrow   = (int*)(w + 4096 + 98304);
  char*  big      = w + 4096 + 131072;
  bf16* xb  = (bf16*)(big);                        // [4096][D]  bf16   8.4 MB
  bf16* W1T = (bf16*)(big + 8388608);              // [E][H][D]  bf16  33.5 MB
  bf16* W2T = (bf16*)(big + 8388608 + 33554432);   // [E][D][H]  bf16  33.5 MB
  bf16* Y1  = (bf16*)(big + 8388608 + 67108864);   // [8192][H]  bf16  33.5 MB
  bf16* Y2  = (bf16*)(big + 8388608);              // alias W1T (dead after GEMM1)

  init_kernel<<<1, 128, 0, stream>>>(counts);
  transpose_cast_kernel<<<dim3(HDIM / 64, DDIM / 64, E), 256, 0, stream>>>(W1, W1T, DDIM, HDIM);
  transpose_cast_kernel<<<dim3(DDIM / 64, HDIM / 64, E), 256, 0, stream>>>(W2, W2T, HDIM, DDIM);
  router_kernel<<<NTOK / 8, 256, 0, stream>>>(x, Wr, br, counts, topk_e, topk_g, xb);
  scan_kernel<<<1, 1, 0, stream>>>(counts, offsets, cursor, blockmap, nblk);
  scatter_kernel<<<NTOK / 256, 256, 0, stream>>>(topk_e, cursor, rowtok, tokrow);
  ffn_gemm<true, true><<<dim3(MAXBLK, HDIM / 128), 256, 0, stream>>>(
      xb, W1T, b1, Y1, rowtok, offsets, counts, blockmap, nblk, DDIM, HDIM);
  ffn_gemm<false, false><<<dim3(MAXBLK, DDIM / 128), 256, 0, stream>>>(
      Y1, W2T, b2, Y2, rowtok, offsets, counts, blockmap, nblk, HDIM, DDIM);
  combine_kernel<<<NTOK * DDIM / 8 / 256, 256, 0, stream>>>(Y2, tokrow, topk_g, out);
}